// Round 4
// baseline (472.033 us; speedup 1.0000x reference)
//
#include <hip/hip_runtime.h>

// Fastfood transform: out = (1/sqrt(d)) * S * H( G * P( H( B * x ) ) )
// d = 1024, rows = 65536, fp32.
//
// One wave per row; lane owns 16 consecutive elements (element n = 16*lane + j).
// WHT-1024 = 4 register stages (element bits 0-3) + 6 lane stages (bits 4-9).
// Lane stages run entirely on the VALU (DPP + gfx950 permlane*_swap), keeping
// the DS pipe free for the single permutation-gather round trip. LDS slices
// are wave-private and same-wave DS ops execute in order -> no barriers.
//
// R3 changes (from R2 counters: VGPR=64 << ~108 live values -> compiler
// re-loads params every row from L2; SQ_LDS_BANK_CONFLICT=10.9M from
// 64B-stride float4 LDS writes):
//  * __launch_bounds__(256,4): VGPR cap 128 so b/g/s/p/t/v all stay in
//    registers (4 blocks/CU resident, >= the ~12 waves/CU we measured)
//  * XOR-swizzled LDS slice: word addr n ^ (((n>>4)&7)<<2). float4 writes
//    stay 16B-contiguous but the 8-lane groups cover all 8 bank-granules
//    -> conflict-free writes. Gather offsets pre-swizzled, packed u16.

constexpr int D = 1024;
constexpr int THREADS = 256;
constexpr int WAVES_PER_BLOCK = 4;
constexpr int ROWS_PER_WAVE = 8;
constexpr int ROWS_PER_BLOCK = WAVES_PER_BLOCK * ROWS_PER_WAVE; // 32

#if defined(__has_builtin)
#if __has_builtin(__builtin_amdgcn_permlane16_swap) && __has_builtin(__builtin_amdgcn_permlane32_swap)
#define HAS_PLSWAP 1
#endif
#endif

// Bank-conflict-breaking swizzle for the 1024-word LDS slice.
// XORs word-address bits [4:2] with bits [6:4] (the low lane bits), so the
// 64B-stride float4 writes of consecutive lanes land on distinct granules.
// Bijective on [0,1024); preserves 4-word (16B) contiguity/alignment.
__device__ __forceinline__ int swz_word(int n) {
    return n ^ (((n >> 4) & 7) << 2);
}

// DPP-based lane permute (VALU, not DS). CTRL: quad_perm / row_* encodings.
template <int CTRL>
__device__ __forceinline__ float dppmov(float x) {
    return __int_as_float(
        __builtin_amdgcn_update_dpp(0, __float_as_int(x), CTRL, 0xF, 0xF, false));
}

// Butterfly helper: new = partner + sgn*own, sgn = -1 on high-side lanes.
__device__ __forceinline__ void fwht1024(float v[16], float sg1, float sg2,
                                         float sg4, float sg8, float sg16,
                                         float sg32) {
    // Register stages h = 1,2,4,8 (element bits 0-3).
    #pragma unroll
    for (int h = 1; h <= 8; h <<= 1) {
        #pragma unroll
        for (int j = 0; j < 16; ++j) {
            if ((j & h) == 0) {
                float a = v[j], c = v[j ^ h];
                v[j]     = a + c;
                v[j ^ h] = a - c;
            }
        }
    }
    // Lane mask 1: quad_perm [1,0,3,2]
    #pragma unroll
    for (int j = 0; j < 16; ++j) {
        float p = dppmov<0xB1>(v[j]);
        v[j] = fmaf(sg1, v[j], p);
    }
    // Lane mask 2: quad_perm [2,3,0,1]
    #pragma unroll
    for (int j = 0; j < 16; ++j) {
        float p = dppmov<0x4E>(v[j]);
        v[j] = fmaf(sg2, v[j], p);
    }
    // Lane mask 4: xor4 = row_half_mirror(xor7) o quad_perm[3,2,1,0](xor3)
    #pragma unroll
    for (int j = 0; j < 16; ++j) {
        float p = dppmov<0x141>(dppmov<0x1B>(v[j]));
        v[j] = fmaf(sg4, v[j], p);
    }
    // Lane mask 8: row_ror:8 (rotate by 8 in group of 16 == xor 8)
    #pragma unroll
    for (int j = 0; j < 16; ++j) {
        float p = dppmov<0x128>(v[j]);
        v[j] = fmaf(sg8, v[j], p);
    }
#ifdef HAS_PLSWAP
    // Lane mask 16: v_permlane16_swap_b32(v, v) -> r[0]=even-row vals, r[1]=odd.
    #pragma unroll
    for (int j = 0; j < 16; ++j) {
        auto r = __builtin_amdgcn_permlane16_swap(__float_as_uint(v[j]),
                                                  __float_as_uint(v[j]), false, false);
        v[j] = fmaf(sg16, __uint_as_float(r[1]), __uint_as_float(r[0]));
    }
    // Lane mask 32: v_permlane32_swap_b32.
    #pragma unroll
    for (int j = 0; j < 16; ++j) {
        auto r = __builtin_amdgcn_permlane32_swap(__float_as_uint(v[j]),
                                                  __float_as_uint(v[j]), false, false);
        v[j] = fmaf(sg32, __uint_as_float(r[1]), __uint_as_float(r[0]));
    }
#else
    #pragma unroll
    for (int j = 0; j < 16; ++j) {
        float p = __shfl_xor(v[j], 16, 64);
        v[j] = fmaf(sg16, v[j], p);
    }
    #pragma unroll
    for (int j = 0; j < 16; ++j) {
        float p = __shfl_xor(v[j], 32, 64);
        v[j] = fmaf(sg32, v[j], p);
    }
#endif
}

__global__ __launch_bounds__(THREADS, 4) void fastfood_kernel(
    const float* __restrict__ x,
    const float* __restrict__ Bv,
    const float* __restrict__ Gv,
    const float* __restrict__ Sv,
    const int*   __restrict__ Pv,
    float* __restrict__ out)
{
    __shared__ float lds[WAVES_PER_BLOCK * D]; // 16 KB, one 4 KB slice per wave

    const int lane  = threadIdx.x & 63;
    const int wave  = threadIdx.x >> 6;
    float* slice    = lds + wave * D;
    const char* sliceb = reinterpret_cast<const char*>(slice);
    const int ebase = lane << 4;

    const float sg1  = (lane & 1)  ? -1.0f : 1.0f;
    const float sg2  = (lane & 2)  ? -1.0f : 1.0f;
    const float sg4  = (lane & 4)  ? -1.0f : 1.0f;
    const float sg8  = (lane & 8)  ? -1.0f : 1.0f;
    const float sg16 = (lane & 16) ? -1.0f : 1.0f;
    const float sg32 = (lane & 32) ? -1.0f : 1.0f;

    // Swizzled write addresses for this lane's four float4 LDS stores
    // (loop-invariant; 4 ints).
    int swaddr[4];
    #pragma unroll
    for (int q = 0; q < 4; ++q)
        swaddr[q] = swz_word(ebase + 4 * q);

    // Row-invariant params into registers (once per wave).
    // Gather offsets pre-swizzled and packed as u16 BYTE offsets (8 VGPRs).
    float b[16], g[16], s[16];
    unsigned po[8];
    #pragma unroll
    for (int q = 0; q < 4; ++q) {
        float4 tb = reinterpret_cast<const float4*>(Bv + ebase)[q];
        float4 tg = reinterpret_cast<const float4*>(Gv + ebase)[q];
        float4 ts = reinterpret_cast<const float4*>(Sv + ebase)[q];
        int4   tp = reinterpret_cast<const int4 *>(Pv + ebase)[q];
        const float inv = 1.0f / 32.0f; // 1/sqrt(1024), SCALE=1
        b[4*q+0]=tb.x; b[4*q+1]=tb.y; b[4*q+2]=tb.z; b[4*q+3]=tb.w;
        g[4*q+0]=tg.x; g[4*q+1]=tg.y; g[4*q+2]=tg.z; g[4*q+3]=tg.w;
        s[4*q+0]=ts.x*inv; s[4*q+1]=ts.y*inv; s[4*q+2]=ts.z*inv; s[4*q+3]=ts.w*inv;
        po[2*q+0] = (unsigned)(swz_word(tp.x) << 2) |
                    ((unsigned)(swz_word(tp.y) << 2) << 16);
        po[2*q+1] = (unsigned)(swz_word(tp.z) << 2) |
                    ((unsigned)(swz_word(tp.w) << 2) << 16);
    }

    const int row0 = blockIdx.x * ROWS_PER_BLOCK + wave;
    const size_t rowstep = (size_t)WAVES_PER_BLOCK * D;
    const float* xr   = x   + (size_t)row0 * D + ebase;
    float*       outr = out + (size_t)row0 * D + ebase;

    // Prologue: prefetch row 0 into t[].
    float t[16];
    #pragma unroll
    for (int q = 0; q < 4; ++q) {
        float4 f = reinterpret_cast<const float4*>(xr)[q];
        t[4*q+0] = f.x; t[4*q+1] = f.y; t[4*q+2] = f.z; t[4*q+3] = f.w;
    }

    for (int i = 0; i < ROWS_PER_WAVE; ++i) {
        // Consume the prefetched row: v = B * x
        float v[16];
        #pragma unroll
        for (int j = 0; j < 16; ++j)
            v[j] = t[j] * b[j];

        // Issue row i+1's global loads NOW so HBM latency hides under the
        // two FWHT chains. WAR on t[] is safe: the v=t*b VALU ops read
        // their operands before the loads write back.
        if (i + 1 < ROWS_PER_WAVE) {
            xr += rowstep;
            #pragma unroll
            for (int q = 0; q < 4; ++q) {
                float4 f = reinterpret_cast<const float4*>(xr)[q];
                t[4*q+0] = f.x; t[4*q+1] = f.y; t[4*q+2] = f.z; t[4*q+3] = f.w;
            }
        }

        fwht1024(v, sg1, sg2, sg4, sg8, sg16, sg32); // H(Bx)

        // Permutation gather through wave-private LDS (same-wave DS ops are
        // in-order: no barrier needed). Swizzled layout: writes hit all 8
        // bank-granules per 8 lanes -> minimum-serialization b128 stores.
        #pragma unroll
        for (int q = 0; q < 4; ++q) {
            reinterpret_cast<float4*>(slice + swaddr[q])[0] =
                make_float4(v[4*q+0], v[4*q+1], v[4*q+2], v[4*q+3]);
        }
        #pragma unroll
        for (int k = 0; k < 8; ++k) {
            const unsigned pk = po[k];
            const float a0 = *reinterpret_cast<const float*>(sliceb + (pk & 0xFFFFu));
            const float a1 = *reinterpret_cast<const float*>(sliceb + (pk >> 16));
            v[2*k+0] = a0 * g[2*k+0]; // G * P(HBx)
            v[2*k+1] = a1 * g[2*k+1];
        }

        fwht1024(v, sg1, sg2, sg4, sg8, sg16, sg32); // H(GPHBx)

        #pragma unroll
        for (int q = 0; q < 4; ++q) {
            float4 o;
            o.x = v[4*q+0] * s[4*q+0];
            o.y = v[4*q+1] * s[4*q+1];
            o.z = v[4*q+2] * s[4*q+2];
            o.w = v[4*q+3] * s[4*q+3];
            reinterpret_cast<float4*>(outr)[q] = o;
        }
        outr += rowstep;
    }
}

extern "C" void kernel_launch(void* const* d_in, const int* in_sizes, int n_in,
                              void* d_out, int out_size, void* d_ws, size_t ws_size,
                              hipStream_t stream) {
    const float* x  = (const float*)d_in[0];
    const float* Bv = (const float*)d_in[1];
    const float* Gv = (const float*)d_in[2];
    const float* Sv = (const float*)d_in[3];
    const int*   Pv = (const int*)d_in[4];
    float* out = (float*)d_out;

    const int nrows  = in_sizes[0] / D;           // 65536
    const int blocks = nrows / ROWS_PER_BLOCK;    // 2048
    fastfood_kernel<<<blocks, THREADS, 0, stream>>>(x, Bv, Gv, Sv, Pv, out);
}

// Round 5
// 471.587 us; speedup vs baseline: 1.0009x; 1.0009x over previous
//
#include <hip/hip_runtime.h>

// Fastfood transform: out = (1/sqrt(d)) * S * H( G * P( H( B * x ) ) )
// d = 1024, rows = 65536, fp32.
//
// One wave per row; lane owns 16 consecutive elements (element n = 16*lane + j).
// WHT-1024 = 4 register stages (element bits 0-3) + 6 lane stages (bits 4-9).
// Lane stages run entirely on the VALU (DPP + gfx950 permlane*_swap), keeping
// the DS pipe free for the single permutation-gather round trip. LDS slices
// are wave-private and same-wave DS ops execute in order -> no barriers.
//
// R4 change (single variable): pin occupancy with amdgpu_waves_per_eu(4,4).
// R3 evidence: VGPR_Count stuck at 64 while ~104 values are live -> compiler
// spills/reloads every row (VALU issue-cycles/row ~1745 vs ~630 algorithmic,
// VALUBusy 56%). launch_bounds' min-waves arg only raises the cap; the
// heuristic still chose 8 waves/EU @ 64 VGPR. Pinning max waves = 4 makes
// 128 VGPRs free of occupancy cost, so params/prefetch stay in registers.
// (R3's LDS swizzle kept: conflicts 10.9M -> 5.9M, off the critical path.)

constexpr int D = 1024;
constexpr int THREADS = 256;
constexpr int WAVES_PER_BLOCK = 4;
constexpr int ROWS_PER_WAVE = 8;
constexpr int ROWS_PER_BLOCK = WAVES_PER_BLOCK * ROWS_PER_WAVE; // 32

#if defined(__has_builtin)
#if __has_builtin(__builtin_amdgcn_permlane16_swap) && __has_builtin(__builtin_amdgcn_permlane32_swap)
#define HAS_PLSWAP 1
#endif
#endif

// Bank-conflict-breaking swizzle for the 1024-word LDS slice.
// XORs word-address bits [4:2] with bits [6:4] (the low lane bits), so the
// 64B-stride float4 writes of consecutive lanes land on distinct granules.
// Bijective on [0,1024); preserves 4-word (16B) contiguity/alignment.
__device__ __forceinline__ int swz_word(int n) {
    return n ^ (((n >> 4) & 7) << 2);
}

// DPP-based lane permute (VALU, not DS). CTRL: quad_perm / row_* encodings.
template <int CTRL>
__device__ __forceinline__ float dppmov(float x) {
    return __int_as_float(
        __builtin_amdgcn_update_dpp(0, __float_as_int(x), CTRL, 0xF, 0xF, false));
}

// Butterfly helper: new = partner + sgn*own, sgn = -1 on high-side lanes.
__device__ __forceinline__ void fwht1024(float v[16], float sg1, float sg2,
                                         float sg4, float sg8, float sg16,
                                         float sg32) {
    // Register stages h = 1,2,4,8 (element bits 0-3).
    #pragma unroll
    for (int h = 1; h <= 8; h <<= 1) {
        #pragma unroll
        for (int j = 0; j < 16; ++j) {
            if ((j & h) == 0) {
                float a = v[j], c = v[j ^ h];
                v[j]     = a + c;
                v[j ^ h] = a - c;
            }
        }
    }
    // Lane mask 1: quad_perm [1,0,3,2]
    #pragma unroll
    for (int j = 0; j < 16; ++j) {
        float p = dppmov<0xB1>(v[j]);
        v[j] = fmaf(sg1, v[j], p);
    }
    // Lane mask 2: quad_perm [2,3,0,1]
    #pragma unroll
    for (int j = 0; j < 16; ++j) {
        float p = dppmov<0x4E>(v[j]);
        v[j] = fmaf(sg2, v[j], p);
    }
    // Lane mask 4: xor4 = row_half_mirror(xor7) o quad_perm[3,2,1,0](xor3)
    #pragma unroll
    for (int j = 0; j < 16; ++j) {
        float p = dppmov<0x141>(dppmov<0x1B>(v[j]));
        v[j] = fmaf(sg4, v[j], p);
    }
    // Lane mask 8: row_ror:8 (rotate by 8 in group of 16 == xor 8)
    #pragma unroll
    for (int j = 0; j < 16; ++j) {
        float p = dppmov<0x128>(v[j]);
        v[j] = fmaf(sg8, v[j], p);
    }
#ifdef HAS_PLSWAP
    // Lane mask 16: v_permlane16_swap_b32(v, v) -> r[0]=even-row vals, r[1]=odd.
    #pragma unroll
    for (int j = 0; j < 16; ++j) {
        auto r = __builtin_amdgcn_permlane16_swap(__float_as_uint(v[j]),
                                                  __float_as_uint(v[j]), false, false);
        v[j] = fmaf(sg16, __uint_as_float(r[1]), __uint_as_float(r[0]));
    }
    // Lane mask 32: v_permlane32_swap_b32.
    #pragma unroll
    for (int j = 0; j < 16; ++j) {
        auto r = __builtin_amdgcn_permlane32_swap(__float_as_uint(v[j]),
                                                  __float_as_uint(v[j]), false, false);
        v[j] = fmaf(sg32, __uint_as_float(r[1]), __uint_as_float(r[0]));
    }
#else
    #pragma unroll
    for (int j = 0; j < 16; ++j) {
        float p = __shfl_xor(v[j], 16, 64);
        v[j] = fmaf(sg16, v[j], p);
    }
    #pragma unroll
    for (int j = 0; j < 16; ++j) {
        float p = __shfl_xor(v[j], 32, 64);
        v[j] = fmaf(sg32, v[j], p);
    }
#endif
}

__global__ __attribute__((amdgpu_waves_per_eu(4, 4)))
__launch_bounds__(THREADS) void fastfood_kernel(
    const float* __restrict__ x,
    const float* __restrict__ Bv,
    const float* __restrict__ Gv,
    const float* __restrict__ Sv,
    const int*   __restrict__ Pv,
    float* __restrict__ out)
{
    __shared__ float lds[WAVES_PER_BLOCK * D]; // 16 KB, one 4 KB slice per wave

    const int lane  = threadIdx.x & 63;
    const int wave  = threadIdx.x >> 6;
    float* slice    = lds + wave * D;
    const char* sliceb = reinterpret_cast<const char*>(slice);
    const int ebase = lane << 4;

    const float sg1  = (lane & 1)  ? -1.0f : 1.0f;
    const float sg2  = (lane & 2)  ? -1.0f : 1.0f;
    const float sg4  = (lane & 4)  ? -1.0f : 1.0f;
    const float sg8  = (lane & 8)  ? -1.0f : 1.0f;
    const float sg16 = (lane & 16) ? -1.0f : 1.0f;
    const float sg32 = (lane & 32) ? -1.0f : 1.0f;

    // Swizzled write addresses for this lane's four float4 LDS stores
    // (loop-invariant; 4 ints).
    int swaddr[4];
    #pragma unroll
    for (int q = 0; q < 4; ++q)
        swaddr[q] = swz_word(ebase + 4 * q);

    // Row-invariant params into registers (once per wave).
    // Gather offsets pre-swizzled and packed as u16 BYTE offsets (8 VGPRs).
    float b[16], g[16], s[16];
    unsigned po[8];
    #pragma unroll
    for (int q = 0; q < 4; ++q) {
        float4 tb = reinterpret_cast<const float4*>(Bv + ebase)[q];
        float4 tg = reinterpret_cast<const float4*>(Gv + ebase)[q];
        float4 ts = reinterpret_cast<const float4*>(Sv + ebase)[q];
        int4   tp = reinterpret_cast<const int4 *>(Pv + ebase)[q];
        const float inv = 1.0f / 32.0f; // 1/sqrt(1024), SCALE=1
        b[4*q+0]=tb.x; b[4*q+1]=tb.y; b[4*q+2]=tb.z; b[4*q+3]=tb.w;
        g[4*q+0]=tg.x; g[4*q+1]=tg.y; g[4*q+2]=tg.z; g[4*q+3]=tg.w;
        s[4*q+0]=ts.x*inv; s[4*q+1]=ts.y*inv; s[4*q+2]=ts.z*inv; s[4*q+3]=ts.w*inv;
        po[2*q+0] = (unsigned)(swz_word(tp.x) << 2) |
                    ((unsigned)(swz_word(tp.y) << 2) << 16);
        po[2*q+1] = (unsigned)(swz_word(tp.z) << 2) |
                    ((unsigned)(swz_word(tp.w) << 2) << 16);
    }

    const int row0 = blockIdx.x * ROWS_PER_BLOCK + wave;
    const size_t rowstep = (size_t)WAVES_PER_BLOCK * D;
    const float* xr   = x   + (size_t)row0 * D + ebase;
    float*       outr = out + (size_t)row0 * D + ebase;

    // Prologue: prefetch row 0 into t[].
    float t[16];
    #pragma unroll
    for (int q = 0; q < 4; ++q) {
        float4 f = reinterpret_cast<const float4*>(xr)[q];
        t[4*q+0] = f.x; t[4*q+1] = f.y; t[4*q+2] = f.z; t[4*q+3] = f.w;
    }

    for (int i = 0; i < ROWS_PER_WAVE; ++i) {
        // Consume the prefetched row: v = B * x
        float v[16];
        #pragma unroll
        for (int j = 0; j < 16; ++j)
            v[j] = t[j] * b[j];

        // Issue row i+1's global loads NOW so HBM latency hides under the
        // two FWHT chains. WAR on t[] is safe: the v=t*b VALU ops read
        // their operands before the loads write back.
        if (i + 1 < ROWS_PER_WAVE) {
            xr += rowstep;
            #pragma unroll
            for (int q = 0; q < 4; ++q) {
                float4 f = reinterpret_cast<const float4*>(xr)[q];
                t[4*q+0] = f.x; t[4*q+1] = f.y; t[4*q+2] = f.z; t[4*q+3] = f.w;
            }
        }

        fwht1024(v, sg1, sg2, sg4, sg8, sg16, sg32); // H(Bx)

        // Permutation gather through wave-private LDS (same-wave DS ops are
        // in-order: no barrier needed). Swizzled layout: writes hit all 8
        // bank-granules per 8 lanes -> minimum-serialization b128 stores.
        #pragma unroll
        for (int q = 0; q < 4; ++q) {
            reinterpret_cast<float4*>(slice + swaddr[q])[0] =
                make_float4(v[4*q+0], v[4*q+1], v[4*q+2], v[4*q+3]);
        }
        #pragma unroll
        for (int k = 0; k < 8; ++k) {
            const unsigned pk = po[k];
            const float a0 = *reinterpret_cast<const float*>(sliceb + (pk & 0xFFFFu));
            const float a1 = *reinterpret_cast<const float*>(sliceb + (pk >> 16));
            v[2*k+0] = a0 * g[2*k+0]; // G * P(HBx)
            v[2*k+1] = a1 * g[2*k+1];
        }

        fwht1024(v, sg1, sg2, sg4, sg8, sg16, sg32); // H(GPHBx)

        #pragma unroll
        for (int q = 0; q < 4; ++q) {
            float4 o;
            o.x = v[4*q+0] * s[4*q+0];
            o.y = v[4*q+1] * s[4*q+1];
            o.z = v[4*q+2] * s[4*q+2];
            o.w = v[4*q+3] * s[4*q+3];
            reinterpret_cast<float4*>(outr)[q] = o;
        }
        outr += rowstep;
    }
}

extern "C" void kernel_launch(void* const* d_in, const int* in_sizes, int n_in,
                              void* d_out, int out_size, void* d_ws, size_t ws_size,
                              hipStream_t stream) {
    const float* x  = (const float*)d_in[0];
    const float* Bv = (const float*)d_in[1];
    const float* Gv = (const float*)d_in[2];
    const float* Sv = (const float*)d_in[3];
    const int*   Pv = (const int*)d_in[4];
    float* out = (float*)d_out;

    const int nrows  = in_sizes[0] / D;           // 65536
    const int blocks = nrows / ROWS_PER_BLOCK;    // 2048
    fastfood_kernel<<<blocks, THREADS, 0, stream>>>(x, Bv, Gv, Sv, Pv, out);
}